// Round 11
// baseline (1453.647 us; speedup 1.0000x reference)
//
#include <hip/hip_runtime.h>
#include <math.h>
#include <stdint.h>

#define B_ 128
#define T_ 1024
#define H_ 256
#define Z_ 64
#define M_ (B_ * T_)   // 131072 rows

typedef float     f4   __attribute__((ext_vector_type(4)));
typedef _Float16  h4_t __attribute__((ext_vector_type(4)));

// ---------------------------------------------------------------------------
// Kernel 1: precompute the non-recurrent part of both matmuls (unchanged).
// ---------------------------------------------------------------------------
__global__ __launch_bounds__(256) void precompute_kernel(
    const float* __restrict__ Hm,    // [M_, 256]
    const float* __restrict__ Wmu,   // [64, 320]
    const float* __restrict__ Wstd,  // [64, 320]
    const float* __restrict__ bmu,   // [64]
    const float* __restrict__ bstd,  // [64]
    float* __restrict__ pre_mu,      // [M_, 64]
    float* __restrict__ pre_std)     // [M_, 64]
{
    const int tid = threadIdx.x;
    const int ty = tid >> 4;
    const int tx = tid & 15;
    const int m0 = blockIdx.x * 64;

    __shared__ float Ash[64][17];
    __shared__ float Wm[64][17];
    __shared__ float Ws[64][17];

    float accm[4][4] = {};
    float accs[4][4] = {};

    const int lrow = tid >> 2;
    const int lk   = (tid & 3) * 4;

    for (int k0 = 0; k0 < 256; k0 += 16) {
        float4 av  = *reinterpret_cast<const float4*>(&Hm[(size_t)(m0 + lrow) * H_ + k0 + lk]);
        float4 wmv = *reinterpret_cast<const float4*>(&Wmu[(size_t)lrow * 320 + k0 + lk]);
        float4 wsv = *reinterpret_cast<const float4*>(&Wstd[(size_t)lrow * 320 + k0 + lk]);
        __syncthreads();
        Ash[lrow][lk + 0] = av.x;  Ash[lrow][lk + 1] = av.y;
        Ash[lrow][lk + 2] = av.z;  Ash[lrow][lk + 3] = av.w;
        Wm[lrow][lk + 0] = wmv.x;  Wm[lrow][lk + 1] = wmv.y;
        Wm[lrow][lk + 2] = wmv.z;  Wm[lrow][lk + 3] = wmv.w;
        Ws[lrow][lk + 0] = wsv.x;  Ws[lrow][lk + 1] = wsv.y;
        Ws[lrow][lk + 2] = wsv.z;  Ws[lrow][lk + 3] = wsv.w;
        __syncthreads();

        #pragma unroll
        for (int kk = 0; kk < 16; ++kk) {
            float a4[4], wm4[4], ws4[4];
            #pragma unroll
            for (int i = 0; i < 4; ++i) a4[i] = Ash[ty * 4 + i][kk];
            #pragma unroll
            for (int jj = 0; jj < 4; ++jj) wm4[jj] = Wm[tx * 4 + jj][kk];
            #pragma unroll
            for (int jj = 0; jj < 4; ++jj) ws4[jj] = Ws[tx * 4 + jj][kk];
            #pragma unroll
            for (int i = 0; i < 4; ++i)
                #pragma unroll
                for (int jj = 0; jj < 4; ++jj) {
                    accm[i][jj] += a4[i] * wm4[jj];
                    accs[i][jj] += a4[i] * ws4[jj];
                }
        }
    }

    float4 bm = *reinterpret_cast<const float4*>(&bmu[tx * 4]);
    float4 bs = *reinterpret_cast<const float4*>(&bstd[tx * 4]);
    #pragma unroll
    for (int i = 0; i < 4; ++i) {
        const size_t m = (size_t)(m0 + ty * 4 + i);
        float4 om, os;
        om.x = accm[i][0] + bm.x;  om.y = accm[i][1] + bm.y;
        om.z = accm[i][2] + bm.z;  om.w = accm[i][3] + bm.w;
        os.x = accs[i][0] + bs.x;  os.y = accs[i][1] + bs.y;
        os.z = accs[i][2] + bs.z;  os.w = accs[i][3] + bs.w;
        *reinterpret_cast<float4*>(&pre_mu[m * Z_ + tx * 4])  = om;
        *reinterpret_cast<float4*>(&pre_std[m * Z_ + tx * 4]) = os;
    }
}

// ---------------------------------------------------------------------------
// async 16B global -> LDS (wave-uniform LDS base; HW writes base + lane*16)
// ---------------------------------------------------------------------------
__device__ __forceinline__ void stage16(const float* g, float* lds_base) {
    __builtin_amdgcn_global_load_lds(
        (const __attribute__((address_space(1))) uint32_t*)(uintptr_t)g,
        (__attribute__((address_space(3))) uint32_t*)(uintptr_t)lds_base,
        16, 0, 0);
}

// ---------------------------------------------------------------------------
// Kernel 2: MFMA recurrence. One wave per 16 batch rows (8 blocks total).
//
// Layout identity (16x16x16 f16): D's (m,lane) mapping == B's (k,lane)
// mapping, so step t's z output feeds step t+1's B operand with only
// f32->f16 converts — the z broadcast costs zero cross-lane ops.
//
// R10 lesson: the 132-VGPR wall is real and the loop's live set (~150+)
// exceeded it -> in-loop scratch spills were the ~2000 cy/step stall, not
// waitcnt conservatism. This version fits UNDER the wall:
//   - pm/ps read (8x ds_read_b128, 32 regs) before MFMA; ev read (4x, 16
//     regs) AFTER the MFMA in a second asm block -> peak live ~112-128.
//   - stage t+4 at iteration END (after all reads of the buffer).
//   - loop-top wait = weakest legal vmcnt(63): current buf's DMA is >= 72
//     vmem-ops old (3 iters x 24), in-order retirement guarantees landed.
//     Prologue vmcnt(12) covers bufs 0-2; buf3 covered by 72-op spacing.
//     Stores are NEVER drained (no vmcnt(0) anywhere in the loop).
// ---------------------------------------------------------------------------
__global__ __launch_bounds__(64)
__attribute__((amdgpu_waves_per_eu(1, 1)))
void recurrent_kernel(
    const float* __restrict__ pre_mu,   // [M_, 64]
    const float* __restrict__ pre_std,  // [M_, 64]
    const float* __restrict__ eps,      // [B_, T_, 64]
    const float* __restrict__ Wmu,      // [64, 320]
    const float* __restrict__ Wstd,     // [64, 320]
    float* __restrict__ out)            // z | mu | std, each [B_, T_, 64]
{
    const int l   = threadIdx.x;
    const int col = l & 15;            // batch row within the 16-group
    const int g   = l >> 4;            // 0..3
    const int b0  = blockIdx.x * 16;

    // ---- A-fragments for both weight matrices: wm/ws[rt][kt], f16 ----
    h4_t wm[4][4], ws[4][4];
    #pragma unroll
    for (int rt = 0; rt < 4; ++rt) {
        #pragma unroll
        for (int kt = 0; kt < 4; ++kt) {
            const size_t off = (size_t)(rt * 16 + col) * 320 + 256 + kt * 16 + 4 * g;
            const f4 a = *reinterpret_cast<const f4*>(&Wmu[off]);
            const f4 s = *reinterpret_cast<const f4*>(&Wstd[off]);
            h4_t wa, wb;
            wa[0] = (_Float16)a[0]; wa[1] = (_Float16)a[1];
            wa[2] = (_Float16)a[2]; wa[3] = (_Float16)a[3];
            wb[0] = (_Float16)s[0]; wb[1] = (_Float16)s[1];
            wb[2] = (_Float16)s[2]; wb[3] = (_Float16)s[3];
            wm[rt][kt] = wa;
            ws[rt][kt] = wb;
        }
    }
    #pragma unroll
    for (int rt = 0; rt < 4; ++rt)
        #pragma unroll
        for (int kt = 0; kt < 4; ++kt) {
            asm volatile("" : "+v"(wm[rt][kt]));
            asm volatile("" : "+v"(ws[rt][kt]));
        }

    // LDS staging ring: 4 bufs x (4 pre_mu + 4 pre_std + 4 eps tiles) x 1KB
    __shared__ float stg[4][12][256];

    float* __restrict__ zo  = out;
    float* __restrict__ muo = out + (size_t)M_ * Z_;
    float* __restrict__ sdo = out + (size_t)2 * M_ * Z_;

    // prologue: stage t = 0..3 (48 vmem ops)
    #pragma unroll
    for (int s = 0; s < 4; ++s) {
        const size_t row = ((size_t)(b0 + col) * T_ + s) * 64 + 4 * g;
        #pragma unroll
        for (int rt = 0; rt < 4; ++rt) {
            stage16(pre_mu  + row + rt * 16, &stg[s][rt][0]);
            stage16(pre_std + row + rt * 16, &stg[s][4 + rt][0]);
            stage16(eps     + row + rt * 16, &stg[s][8 + rt][0]);
        }
    }
    // retire bufs 0,1,2 (all but the newest 12 = buf3's loads)
    asm volatile("s_waitcnt vmcnt(12)");

    // z_{-1} = 0 as B fragments
    h4_t zb[4];
    #pragma unroll
    for (int i = 0; i < 4; ++i)
        zb[i] = (h4_t){(_Float16)0, (_Float16)0, (_Float16)0, (_Float16)0};

    int sbuf = 0;
    for (int t = 0; t < T_; ++t) {
        // weakest legal wait: this buf's DMA is >= 72 vmem-ops old -> landed.
        asm volatile("s_waitcnt vmcnt(63)");

        const unsigned a32 =
            (unsigned)(uintptr_t)&stg[sbuf][0][0] + 16u * (unsigned)l;

        // pm/ps reads only (32 regs), wait INSIDE the block.
        f4 pm0, pm1, pm2, pm3, ps0, ps1, ps2, ps3;
        asm volatile(
            "ds_read_b128 %0, %8 offset:0\n\t"
            "ds_read_b128 %1, %8 offset:1024\n\t"
            "ds_read_b128 %2, %8 offset:2048\n\t"
            "ds_read_b128 %3, %8 offset:3072\n\t"
            "ds_read_b128 %4, %8 offset:4096\n\t"
            "ds_read_b128 %5, %8 offset:5120\n\t"
            "ds_read_b128 %6, %8 offset:6144\n\t"
            "ds_read_b128 %7, %8 offset:7168\n\t"
            "s_waitcnt lgkmcnt(0)"
            : "=&v"(pm0), "=&v"(pm1), "=&v"(pm2), "=&v"(pm3),
              "=&v"(ps0), "=&v"(ps1), "=&v"(ps2), "=&v"(ps3)
            : "v"(a32));
        __builtin_amdgcn_sched_barrier(0);

        // D = W * z_{t-1} + pre   (C-init = pre fragments; 4-deep k chains)
        f4 am[4] = {pm0, pm1, pm2, pm3};
        f4 as_[4] = {ps0, ps1, ps2, ps3};
        #pragma unroll
        for (int kt = 0; kt < 4; ++kt) {
            #pragma unroll
            for (int rt = 0; rt < 4; ++rt) {
                am[rt]  = __builtin_amdgcn_mfma_f32_16x16x16f16(wm[rt][kt], zb[kt], am[rt],  0, 0, 0);
                as_[rt] = __builtin_amdgcn_mfma_f32_16x16x16f16(ws[rt][kt], zb[kt], as_[rt], 0, 0, 0);
            }
        }

        // eps reads (16 regs) only now -> lower peak pressure.
        f4 ev0, ev1, ev2, ev3;
        asm volatile(
            "ds_read_b128 %0, %4 offset:8192\n\t"
            "ds_read_b128 %1, %4 offset:9216\n\t"
            "ds_read_b128 %2, %4 offset:10240\n\t"
            "ds_read_b128 %3, %4 offset:11264\n\t"
            "s_waitcnt lgkmcnt(0)"
            : "=&v"(ev0), "=&v"(ev1), "=&v"(ev2), "=&v"(ev3)
            : "v"(a32));
        __builtin_amdgcn_sched_barrier(0);
        const f4 evv[4] = {ev0, ev1, ev2, ev3};

        // epilogue: softplus, z, stores, and z -> f16 B-fragments for t+1
        const size_t orow = ((size_t)(b0 + col) * T_ + t) * 64 + 4 * g;
        #pragma unroll
        for (int rt = 0; rt < 4; ++rt) {
            const f4 mu4 = am[rt];
            const f4 sx4 = as_[rt];
            const f4 ev4 = evv[rt];
            f4 sd4, z4;
            h4_t zz;
            #pragma unroll
            for (int i = 0; i < 4; ++i) {
                const float sx = sx4[i];
                const float sp = (sx > 20.0f) ? sx : __logf(1.0f + __expf(sx));
                const float sd = sp + 1e-4f;
                sd4[i] = sd;
                const float zi = fmaf(ev4[i], sd, mu4[i]);
                z4[i]  = zi;
                zz[i]  = (_Float16)zi;
            }
            *reinterpret_cast<f4*>(&zo[orow + rt * 16])  = z4;
            *reinterpret_cast<f4*>(&muo[orow + rt * 16]) = mu4;
            *reinterpret_cast<f4*>(&sdo[orow + rt * 16]) = sd4;
            zb[rt] = zz;
        }
        __builtin_amdgcn_sched_barrier(0);

        // stage t+4 into this (fully consumed) buffer — at iteration END so
        // its spacing to the next read of this buf is 3 iterations (72 ops).
        if (t + 4 < T_) {
            const size_t row = ((size_t)(b0 + col) * T_ + (t + 4)) * 64 + 4 * g;
            #pragma unroll
            for (int rt = 0; rt < 4; ++rt) {
                stage16(pre_mu  + row + rt * 16, &stg[sbuf][rt][0]);
                stage16(pre_std + row + rt * 16, &stg[sbuf][4 + rt][0]);
                stage16(eps     + row + rt * 16, &stg[sbuf][8 + rt][0]);
            }
        }

        sbuf = (sbuf + 1) & 3;
    }
}

extern "C" void kernel_launch(void* const* d_in, const int* in_sizes, int n_in,
                              void* d_out, int out_size, void* d_ws, size_t ws_size,
                              hipStream_t stream) {
    const float* input_q = (const float*)d_in[0];  // [B, T, H]
    const float* eps     = (const float*)d_in[1];  // [B, T, Z]
    const float* W_mu    = (const float*)d_in[2];  // [Z, H+Z]
    const float* b_mu    = (const float*)d_in[3];  // [Z]
    const float* W_std   = (const float*)d_in[4];  // [Z, H+Z]
    const float* b_std   = (const float*)d_in[5];  // [Z]
    float* out = (float*)d_out;

    float* pre_mu  = (float*)d_ws;                      // [M_, 64]
    float* pre_std = pre_mu + (size_t)M_ * Z_;          // [M_, 64]

    precompute_kernel<<<M_ / 64, 256, 0, stream>>>(
        input_q, W_mu, W_std, b_mu, b_std, pre_mu, pre_std);

    recurrent_kernel<<<B_ / 16, 64, 0, stream>>>(
        pre_mu, pre_std, eps, W_mu, W_std, out);
}

// Round 12
// 903.730 us; speedup vs baseline: 1.6085x; 1.6085x over previous
//
#include <hip/hip_runtime.h>
#include <math.h>
#include <stdint.h>

#define B_ 128
#define T_ 1024
#define H_ 256
#define Z_ 64
#define M_ (B_ * T_)   // 131072 rows

typedef float     f4   __attribute__((ext_vector_type(4)));
typedef _Float16  h4_t __attribute__((ext_vector_type(4)));

// ---------------------------------------------------------------------------
// Kernel 1: precompute the non-recurrent part of both matmuls (unchanged).
// ---------------------------------------------------------------------------
__global__ __launch_bounds__(256) void precompute_kernel(
    const float* __restrict__ Hm,    // [M_, 256]
    const float* __restrict__ Wmu,   // [64, 320]
    const float* __restrict__ Wstd,  // [64, 320]
    const float* __restrict__ bmu,   // [64]
    const float* __restrict__ bstd,  // [64]
    float* __restrict__ pre_mu,      // [M_, 64]
    float* __restrict__ pre_std)     // [M_, 64]
{
    const int tid = threadIdx.x;
    const int ty = tid >> 4;
    const int tx = tid & 15;
    const int m0 = blockIdx.x * 64;

    __shared__ float Ash[64][17];
    __shared__ float Wm[64][17];
    __shared__ float Ws[64][17];

    float accm[4][4] = {};
    float accs[4][4] = {};

    const int lrow = tid >> 2;
    const int lk   = (tid & 3) * 4;

    for (int k0 = 0; k0 < 256; k0 += 16) {
        float4 av  = *reinterpret_cast<const float4*>(&Hm[(size_t)(m0 + lrow) * H_ + k0 + lk]);
        float4 wmv = *reinterpret_cast<const float4*>(&Wmu[(size_t)lrow * 320 + k0 + lk]);
        float4 wsv = *reinterpret_cast<const float4*>(&Wstd[(size_t)lrow * 320 + k0 + lk]);
        __syncthreads();
        Ash[lrow][lk + 0] = av.x;  Ash[lrow][lk + 1] = av.y;
        Ash[lrow][lk + 2] = av.z;  Ash[lrow][lk + 3] = av.w;
        Wm[lrow][lk + 0] = wmv.x;  Wm[lrow][lk + 1] = wmv.y;
        Wm[lrow][lk + 2] = wmv.z;  Wm[lrow][lk + 3] = wmv.w;
        Ws[lrow][lk + 0] = wsv.x;  Ws[lrow][lk + 1] = wsv.y;
        Ws[lrow][lk + 2] = wsv.z;  Ws[lrow][lk + 3] = wsv.w;
        __syncthreads();

        #pragma unroll
        for (int kk = 0; kk < 16; ++kk) {
            float a4[4], wm4[4], ws4[4];
            #pragma unroll
            for (int i = 0; i < 4; ++i) a4[i] = Ash[ty * 4 + i][kk];
            #pragma unroll
            for (int jj = 0; jj < 4; ++jj) wm4[jj] = Wm[tx * 4 + jj][kk];
            #pragma unroll
            for (int jj = 0; jj < 4; ++jj) ws4[jj] = Ws[tx * 4 + jj][kk];
            #pragma unroll
            for (int i = 0; i < 4; ++i)
                #pragma unroll
                for (int jj = 0; jj < 4; ++jj) {
                    accm[i][jj] += a4[i] * wm4[jj];
                    accs[i][jj] += a4[i] * ws4[jj];
                }
        }
    }

    float4 bm = *reinterpret_cast<const float4*>(&bmu[tx * 4]);
    float4 bs = *reinterpret_cast<const float4*>(&bstd[tx * 4]);
    #pragma unroll
    for (int i = 0; i < 4; ++i) {
        const size_t m = (size_t)(m0 + ty * 4 + i);
        float4 om, os;
        om.x = accm[i][0] + bm.x;  om.y = accm[i][1] + bm.y;
        om.z = accm[i][2] + bm.z;  om.w = accm[i][3] + bm.w;
        os.x = accs[i][0] + bs.x;  os.y = accs[i][1] + bs.y;
        os.z = accs[i][2] + bs.z;  os.w = accs[i][3] + bs.w;
        *reinterpret_cast<float4*>(&pre_mu[m * Z_ + tx * 4])  = om;
        *reinterpret_cast<float4*>(&pre_std[m * Z_ + tx * 4]) = os;
    }
}

// ---------------------------------------------------------------------------
// Kernel 2: MFMA recurrence, 4-wave rt-split. 8 blocks x 256 threads.
//
// R11 lesson: the 1-wave MFMA step is ISSUE-bound (~1100 cy of instructions
// on one SIMD), not latency-bound. Split the step across 4 waves (one per
// 16-row output tile rt=w): each wave does 8 MFMAs + 4 softplus/lane +
// 3 stores + 3 prefetch loads (~300 cy issue), on 4 different SIMDs.
//
// z exchange: tiny LDS tile zbuf[2][16 cols][72] f16 (pad 72 -> <=2-way bank
// conflicts, free per m136). Wave w writes its 16-row slice as one
// ds_write_b64/lane; sync = "s_waitcnt lgkmcnt(0); s_barrier" in ONE asm
// block — raw s_barrier does NOT drain vmcnt (R1 lesson: __syncthreads
// does, putting store latency on the serial path). Double-buffered z ->
// one barrier per step.
//
// B-fragment identity (validated by R9-R11 passing): for 16x16x16 f16,
// B tile kt needs lane l to hold z[kt*16 + 4*(l>>4)+i][l&15] — one
// ds_read_b64 at col*144 + (kt*16+4g)*2.
//
// pre/eps: plain register prefetch depth 3 (9 f4 = 36 VGPRs — affordable
// now that per-wave state is ~110 regs; no global_load_lds, so no hidden
// compiler vmcnt(0) on DMA-written LDS (R9 lesson)). All addressing 32-bit.
// ---------------------------------------------------------------------------
__global__ __launch_bounds__(256)
__attribute__((amdgpu_waves_per_eu(1, 1)))
void recurrent_kernel(
    const float* __restrict__ pre_mu,   // [M_, 64]
    const float* __restrict__ pre_std,  // [M_, 64]
    const float* __restrict__ eps,      // [B_, T_, 64]
    const float* __restrict__ Wmu,      // [64, 320]
    const float* __restrict__ Wstd,     // [64, 320]
    float* __restrict__ out)            // z | mu | std, each [B_, T_, 64]
{
    const int tid = threadIdx.x;
    const int w   = tid >> 6;          // wave = output row tile rt
    const int l   = tid & 63;
    const int col = l & 15;            // batch row within the 16-group
    const int g   = (l >> 4) & 3;      // 0..3
    const int b0  = blockIdx.x * 16;

    // A-fragments, rows [16w,16w+16): wa/wsd[kt], 8 x h4 = 16 VGPRs.
    h4_t wa[4], wsd[4];
    #pragma unroll
    for (int kt = 0; kt < 4; ++kt) {
        const int off = (w * 16 + col) * 320 + 256 + kt * 16 + 4 * g;
        const f4 a = *reinterpret_cast<const f4*>(&Wmu[off]);
        const f4 s = *reinterpret_cast<const f4*>(&Wstd[off]);
        h4_t ha, hs;
        ha[0] = (_Float16)a[0]; ha[1] = (_Float16)a[1];
        ha[2] = (_Float16)a[2]; ha[3] = (_Float16)a[3];
        hs[0] = (_Float16)s[0]; hs[1] = (_Float16)s[1];
        hs[2] = (_Float16)s[2]; hs[3] = (_Float16)s[3];
        wa[kt] = ha;  wsd[kt] = hs;
        asm volatile("" : "+v"(wa[kt]));
        asm volatile("" : "+v"(wsd[kt]));
    }

    // z exchange tile: [buf][col][row], row-pad 64->72 (144B col stride)
    __shared__ _Float16 zbuf[2][16][72];
    for (int i = tid; i < 2 * 16 * 72; i += 256)
        (&zbuf[0][0][0])[i] = (_Float16)0.0f;
    __syncthreads();   // one-time init barrier (outside loop: drain is fine)

    float* __restrict__ zo  = out;
    float* __restrict__ muo = out + M_ * Z_;
    float* __restrict__ sdo = out + 2 * M_ * Z_;

    // this wave's global row slot: ((b0+col)*T + t)*64 + 16w + 4g
    const int rbase = ((b0 + col) * T_) * 64 + 16 * w + 4 * g;

    // register prefetch, depth 3
    f4 pmA, pmB, pmC, psA, psB, psC, evA, evB, evC;
    pmA = *reinterpret_cast<const f4*>(&pre_mu [rbase]);
    psA = *reinterpret_cast<const f4*>(&pre_std[rbase]);
    evA = *reinterpret_cast<const f4*>(&eps    [rbase]);
    pmB = *reinterpret_cast<const f4*>(&pre_mu [rbase + 64]);
    psB = *reinterpret_cast<const f4*>(&pre_std[rbase + 64]);
    evB = *reinterpret_cast<const f4*>(&eps    [rbase + 64]);
    pmC = *reinterpret_cast<const f4*>(&pre_mu [rbase + 128]);
    psC = *reinterpret_cast<const f4*>(&pre_std[rbase + 128]);
    evC = *reinterpret_cast<const f4*>(&eps    [rbase + 128]);

    const int zrd = col * 144 + 8 * g;          // byte addr base for B-frags
    const int zwr = col * 144 + (16 * w + 4 * g) * 2;

    for (int t = 0; t < T_; ++t) {
        // prefetch t+3
        f4 pmN, psN, evN;
        {
            const int idx = rbase + ((t + 3 < T_) ? (t + 3) : t) * 64;
            pmN = *reinterpret_cast<const f4*>(&pre_mu [idx]);
            psN = *reinterpret_cast<const f4*>(&pre_std[idx]);
            evN = *reinterpret_cast<const f4*>(&eps    [idx]);
        }

        // B-fragments of z_{t-1} from LDS (4x ds_read_b64, <=2-way banks)
        const _Float16* zc = &zbuf[t & 1][0][0];
        h4_t zk0 = *reinterpret_cast<const h4_t*>(
            reinterpret_cast<const char*>(zc) + zrd);
        h4_t zk1 = *reinterpret_cast<const h4_t*>(
            reinterpret_cast<const char*>(zc) + zrd + 32);
        h4_t zk2 = *reinterpret_cast<const h4_t*>(
            reinterpret_cast<const char*>(zc) + zrd + 64);
        h4_t zk3 = *reinterpret_cast<const h4_t*>(
            reinterpret_cast<const char*>(zc) + zrd + 96);

        // D = W * z + pre (two independent 4-deep chains)
        f4 am = pmA, as_ = psA;
        am  = __builtin_amdgcn_mfma_f32_16x16x16f16(wa[0],  zk0, am,  0, 0, 0);
        as_ = __builtin_amdgcn_mfma_f32_16x16x16f16(wsd[0], zk0, as_, 0, 0, 0);
        am  = __builtin_amdgcn_mfma_f32_16x16x16f16(wa[1],  zk1, am,  0, 0, 0);
        as_ = __builtin_amdgcn_mfma_f32_16x16x16f16(wsd[1], zk1, as_, 0, 0, 0);
        am  = __builtin_amdgcn_mfma_f32_16x16x16f16(wa[2],  zk2, am,  0, 0, 0);
        as_ = __builtin_amdgcn_mfma_f32_16x16x16f16(wsd[2], zk2, as_, 0, 0, 0);
        am  = __builtin_amdgcn_mfma_f32_16x16x16f16(wa[3],  zk3, am,  0, 0, 0);
        as_ = __builtin_amdgcn_mfma_f32_16x16x16f16(wsd[3], zk3, as_, 0, 0, 0);

        // epilogue: softplus, z, stores (4 values per lane)
        f4 sd4, z4;
        h4_t zz;
        #pragma unroll
        for (int i = 0; i < 4; ++i) {
            const float sx = as_[i];
            const float sp = (sx > 20.0f) ? sx : __logf(1.0f + __expf(sx));
            const float sd = sp + 1e-4f;
            sd4[i] = sd;
            const float zi = fmaf(evA[i], sd, am[i]);
            z4[i] = zi;
            zz[i] = (_Float16)zi;
        }
        const int o = rbase + t * 64;
        *reinterpret_cast<f4*>(&zo[o])  = z4;
        *reinterpret_cast<f4*>(&muo[o]) = am;
        *reinterpret_cast<f4*>(&sdo[o]) = sd4;

        // publish z slice for t+1, then sync WITHOUT draining vmcnt
        *reinterpret_cast<h4_t*>(
            reinterpret_cast<char*>(&zbuf[(t + 1) & 1][0][0]) + zwr) = zz;
        asm volatile("s_waitcnt lgkmcnt(0)\n\ts_barrier" ::: "memory");

        pmA = pmB; psA = psB; evA = evB;
        pmB = pmC; psB = psC; evB = evC;
        pmC = pmN; psC = psN; evC = evN;
    }
}

extern "C" void kernel_launch(void* const* d_in, const int* in_sizes, int n_in,
                              void* d_out, int out_size, void* d_ws, size_t ws_size,
                              hipStream_t stream) {
    const float* input_q = (const float*)d_in[0];  // [B, T, H]
    const float* eps     = (const float*)d_in[1];  // [B, T, Z]
    const float* W_mu    = (const float*)d_in[2];  // [Z, H+Z]
    const float* b_mu    = (const float*)d_in[3];  // [Z]
    const float* W_std   = (const float*)d_in[4];  // [Z, H+Z]
    const float* b_std   = (const float*)d_in[5];  // [Z]
    float* out = (float*)d_out;

    float* pre_mu  = (float*)d_ws;                      // [M_, 64]
    float* pre_std = pre_mu + (size_t)M_ * Z_;          // [M_, 64]

    precompute_kernel<<<M_ / 64, 256, 0, stream>>>(
        input_q, W_mu, W_std, b_mu, b_std, pre_mu, pre_std);

    recurrent_kernel<<<B_ / 16, 256, 0, stream>>>(
        pre_mu, pre_std, eps, W_mu, W_std, out);
}

// Round 13
// 853.724 us; speedup vs baseline: 1.7027x; 1.0586x over previous
//
#include <hip/hip_runtime.h>
#include <math.h>
#include <stdint.h>

#define B_ 128
#define T_ 1024
#define H_ 256
#define Z_ 64
#define M_ (B_ * T_)   // 131072 rows

typedef float     f4   __attribute__((ext_vector_type(4)));
typedef _Float16  h4_t __attribute__((ext_vector_type(4)));

// ---------------------------------------------------------------------------
// Kernel 1: precompute the non-recurrent part of both matmuls (unchanged).
// ---------------------------------------------------------------------------
__global__ __launch_bounds__(256) void precompute_kernel(
    const float* __restrict__ Hm,    // [M_, 256]
    const float* __restrict__ Wmu,   // [64, 320]
    const float* __restrict__ Wstd,  // [64, 320]
    const float* __restrict__ bmu,   // [64]
    const float* __restrict__ bstd,  // [64]
    float* __restrict__ pre_mu,      // [M_, 64]
    float* __restrict__ pre_std)     // [M_, 64]
{
    const int tid = threadIdx.x;
    const int ty = tid >> 4;
    const int tx = tid & 15;
    const int m0 = blockIdx.x * 64;

    __shared__ float Ash[64][17];
    __shared__ float Wm[64][17];
    __shared__ float Ws[64][17];

    float accm[4][4] = {};
    float accs[4][4] = {};

    const int lrow = tid >> 2;
    const int lk   = (tid & 3) * 4;

    for (int k0 = 0; k0 < 256; k0 += 16) {
        float4 av  = *reinterpret_cast<const float4*>(&Hm[(size_t)(m0 + lrow) * H_ + k0 + lk]);
        float4 wmv = *reinterpret_cast<const float4*>(&Wmu[(size_t)lrow * 320 + k0 + lk]);
        float4 wsv = *reinterpret_cast<const float4*>(&Wstd[(size_t)lrow * 320 + k0 + lk]);
        __syncthreads();
        Ash[lrow][lk + 0] = av.x;  Ash[lrow][lk + 1] = av.y;
        Ash[lrow][lk + 2] = av.z;  Ash[lrow][lk + 3] = av.w;
        Wm[lrow][lk + 0] = wmv.x;  Wm[lrow][lk + 1] = wmv.y;
        Wm[lrow][lk + 2] = wmv.z;  Wm[lrow][lk + 3] = wmv.w;
        Ws[lrow][lk + 0] = wsv.x;  Ws[lrow][lk + 1] = wsv.y;
        Ws[lrow][lk + 2] = wsv.z;  Ws[lrow][lk + 3] = wsv.w;
        __syncthreads();

        #pragma unroll
        for (int kk = 0; kk < 16; ++kk) {
            float a4[4], wm4[4], ws4[4];
            #pragma unroll
            for (int i = 0; i < 4; ++i) a4[i] = Ash[ty * 4 + i][kk];
            #pragma unroll
            for (int jj = 0; jj < 4; ++jj) wm4[jj] = Wm[tx * 4 + jj][kk];
            #pragma unroll
            for (int jj = 0; jj < 4; ++jj) ws4[jj] = Ws[tx * 4 + jj][kk];
            #pragma unroll
            for (int i = 0; i < 4; ++i)
                #pragma unroll
                for (int jj = 0; jj < 4; ++jj) {
                    accm[i][jj] += a4[i] * wm4[jj];
                    accs[i][jj] += a4[i] * ws4[jj];
                }
        }
    }

    float4 bm = *reinterpret_cast<const float4*>(&bmu[tx * 4]);
    float4 bs = *reinterpret_cast<const float4*>(&bstd[tx * 4]);
    #pragma unroll
    for (int i = 0; i < 4; ++i) {
        const size_t m = (size_t)(m0 + ty * 4 + i);
        float4 om, os;
        om.x = accm[i][0] + bm.x;  om.y = accm[i][1] + bm.y;
        om.z = accm[i][2] + bm.z;  om.w = accm[i][3] + bm.w;
        os.x = accs[i][0] + bs.x;  os.y = accs[i][1] + bs.y;
        os.z = accs[i][2] + bs.z;  os.w = accs[i][3] + bs.w;
        *reinterpret_cast<float4*>(&pre_mu[m * Z_ + tx * 4])  = om;
        *reinterpret_cast<float4*>(&pre_std[m * Z_ + tx * 4]) = os;
    }
}

// ---------------------------------------------------------------------------
// Kernel 2: MFMA recurrence, 4-wave rt-split, STATE-ONLY output.
//
// R12 lesson: with 3 f4 global stores per lane per step, the compiler must
// vmcnt-wait before reusing the store-data registers next iteration ->
// store-retire latency lands on the serial chain (~1300 cy/step unexplained
// stall). Fix: the recurrence stores ONLY the 8-byte f16 state zz (z16
// buffer); mu/std/z f32 outputs are recomputed feed-forward by
// finalize_kernel from z16 with identical f16 math -> identical results.
//
// Everything else per R11/R12: 4 waves split the 64 z-outputs (wave w = rows
// [16w,16w+16)); z exchanged via padded LDS tile; sync is raw
// "lgkmcnt(0); s_barrier" (NO __syncthreads -> no vmcnt drain, R1); B/D
// fragment identity feeds z back with only f32->f16 converts.
// ---------------------------------------------------------------------------
__global__ __launch_bounds__(256)
__attribute__((amdgpu_waves_per_eu(1, 1)))
void recurrent_kernel(
    const float* __restrict__ pre_mu,   // [M_, 64]
    const float* __restrict__ pre_std,  // [M_, 64]
    const float* __restrict__ eps,      // [B_, T_, 64]
    const float* __restrict__ Wmu,      // [64, 320]
    const float* __restrict__ Wstd,     // [64, 320]
    _Float16* __restrict__ z16)         // [B_, T_, 64] f16 state
{
    const int tid = threadIdx.x;
    const int w   = tid >> 6;          // wave = output row tile rt
    const int l   = tid & 63;
    const int col = l & 15;            // batch row within the 16-group
    const int g   = (l >> 4) & 3;      // 0..3
    const int b0  = blockIdx.x * 16;

    // A-fragments, rows [16w,16w+16): wa/wsd[kt], 8 x h4 = 16 VGPRs.
    h4_t wa[4], wsd[4];
    #pragma unroll
    for (int kt = 0; kt < 4; ++kt) {
        const int off = (w * 16 + col) * 320 + 256 + kt * 16 + 4 * g;
        const f4 a = *reinterpret_cast<const f4*>(&Wmu[off]);
        const f4 s = *reinterpret_cast<const f4*>(&Wstd[off]);
        h4_t ha, hs;
        ha[0] = (_Float16)a[0]; ha[1] = (_Float16)a[1];
        ha[2] = (_Float16)a[2]; ha[3] = (_Float16)a[3];
        hs[0] = (_Float16)s[0]; hs[1] = (_Float16)s[1];
        hs[2] = (_Float16)s[2]; hs[3] = (_Float16)s[3];
        wa[kt] = ha;  wsd[kt] = hs;
        asm volatile("" : "+v"(wa[kt]));
        asm volatile("" : "+v"(wsd[kt]));
    }

    // z exchange tile: [buf][col][row], row-pad 64->72 (144B col stride)
    __shared__ _Float16 zbuf[2][16][72];
    for (int i = tid; i < 2 * 16 * 72; i += 256)
        (&zbuf[0][0][0])[i] = (_Float16)0.0f;
    __syncthreads();   // one-time init barrier (outside loop: drain is fine)

    // this wave's global row slot: ((b0+col)*T + t)*64 + 16w + 4g
    const int rbase = ((b0 + col) * T_) * 64 + 16 * w + 4 * g;

    // register prefetch, depth 3
    f4 pmA, pmB, pmC, psA, psB, psC, evA, evB, evC;
    pmA = *reinterpret_cast<const f4*>(&pre_mu [rbase]);
    psA = *reinterpret_cast<const f4*>(&pre_std[rbase]);
    evA = *reinterpret_cast<const f4*>(&eps    [rbase]);
    pmB = *reinterpret_cast<const f4*>(&pre_mu [rbase + 64]);
    psB = *reinterpret_cast<const f4*>(&pre_std[rbase + 64]);
    evB = *reinterpret_cast<const f4*>(&eps    [rbase + 64]);
    pmC = *reinterpret_cast<const f4*>(&pre_mu [rbase + 128]);
    psC = *reinterpret_cast<const f4*>(&pre_std[rbase + 128]);
    evC = *reinterpret_cast<const f4*>(&eps    [rbase + 128]);

    const int zrd = col * 144 + 8 * g;          // byte addr base for B-frags
    const int zwr = col * 144 + (16 * w + 4 * g) * 2;

    for (int t = 0; t < T_; ++t) {
        // prefetch t+3
        f4 pmN, psN, evN;
        {
            const int idx = rbase + ((t + 3 < T_) ? (t + 3) : t) * 64;
            pmN = *reinterpret_cast<const f4*>(&pre_mu [idx]);
            psN = *reinterpret_cast<const f4*>(&pre_std[idx]);
            evN = *reinterpret_cast<const f4*>(&eps    [idx]);
        }

        // B-fragments of z_{t-1} from LDS (4x ds_read_b64, <=2-way banks)
        const _Float16* zc = &zbuf[t & 1][0][0];
        h4_t zk0 = *reinterpret_cast<const h4_t*>(
            reinterpret_cast<const char*>(zc) + zrd);
        h4_t zk1 = *reinterpret_cast<const h4_t*>(
            reinterpret_cast<const char*>(zc) + zrd + 32);
        h4_t zk2 = *reinterpret_cast<const h4_t*>(
            reinterpret_cast<const char*>(zc) + zrd + 64);
        h4_t zk3 = *reinterpret_cast<const h4_t*>(
            reinterpret_cast<const char*>(zc) + zrd + 96);

        // D = W * z + pre (two independent 4-deep chains)
        f4 am = pmA, as_ = psA;
        am  = __builtin_amdgcn_mfma_f32_16x16x16f16(wa[0],  zk0, am,  0, 0, 0);
        as_ = __builtin_amdgcn_mfma_f32_16x16x16f16(wsd[0], zk0, as_, 0, 0, 0);
        am  = __builtin_amdgcn_mfma_f32_16x16x16f16(wa[1],  zk1, am,  0, 0, 0);
        as_ = __builtin_amdgcn_mfma_f32_16x16x16f16(wsd[1], zk1, as_, 0, 0, 0);
        am  = __builtin_amdgcn_mfma_f32_16x16x16f16(wa[2],  zk2, am,  0, 0, 0);
        as_ = __builtin_amdgcn_mfma_f32_16x16x16f16(wsd[2], zk2, as_, 0, 0, 0);
        am  = __builtin_amdgcn_mfma_f32_16x16x16f16(wa[3],  zk3, am,  0, 0, 0);
        as_ = __builtin_amdgcn_mfma_f32_16x16x16f16(wsd[3], zk3, as_, 0, 0, 0);

        // epilogue: softplus, z (STATE ONLY: no f32 output stores here)
        h4_t zz;
        #pragma unroll
        for (int i = 0; i < 4; ++i) {
            const float sx = as_[i];
            const float sp = (sx > 20.0f) ? sx : __logf(1.0f + __expf(sx));
            const float sd = sp + 1e-4f;
            zz[i] = (_Float16)fmaf(evA[i], sd, am[i]);
        }

        // publish z slice for t+1 (LDS), persist state (8B global store)
        *reinterpret_cast<h4_t*>(
            reinterpret_cast<char*>(&zbuf[(t + 1) & 1][0][0]) + zwr) = zz;
        *reinterpret_cast<h4_t*>(&z16[rbase + t * 64]) = zz;

        // sync WITHOUT draining vmcnt (raw barrier, not __syncthreads)
        asm volatile("s_waitcnt lgkmcnt(0)\n\ts_barrier" ::: "memory");

        pmA = pmB; psA = psB; evA = evB;
        pmB = pmC; psB = psC; evB = evC;
        pmC = pmN; psC = psN; evC = evN;
    }
}

// ---------------------------------------------------------------------------
// Kernel 3: feed-forward finalize. Recomputes mu/std/z for every (b,t) from
// the stored f16 state z16[b,t-1] with the SAME f16 fragments as the
// recurrence -> outputs identical to what the recurrent kernel computed.
// Massively parallel: 8192 blocks x 4 waves; each block does 16 bt-rows,
// wave w computes output rows [16w,16w+16). One iteration of the recurrent
// loop, minus LDS exchange/barrier, with B sourced from z16 (t-1, guarded).
// ---------------------------------------------------------------------------
__global__ __launch_bounds__(256) void finalize_kernel(
    const float* __restrict__ pre_mu,   // [M_, 64]
    const float* __restrict__ pre_std,  // [M_, 64]
    const float* __restrict__ eps,      // [B_, T_, 64]
    const float* __restrict__ Wmu,      // [64, 320]
    const float* __restrict__ Wstd,     // [64, 320]
    const _Float16* __restrict__ z16,   // [B_, T_, 64]
    float* __restrict__ out)            // z | mu | std, each [B_, T_, 64]
{
    const int tid = threadIdx.x;
    const int w   = tid >> 6;
    const int l   = tid & 63;
    const int col = l & 15;
    const int g   = (l >> 4) & 3;
    const int m0  = blockIdx.x * 16;

    // A-fragments, rows [16w,16w+16)
    h4_t wa[4], wsd[4];
    #pragma unroll
    for (int kt = 0; kt < 4; ++kt) {
        const int off = (w * 16 + col) * 320 + 256 + kt * 16 + 4 * g;
        const f4 a = *reinterpret_cast<const f4*>(&Wmu[off]);
        const f4 s = *reinterpret_cast<const f4*>(&Wstd[off]);
        h4_t ha, hs;
        ha[0] = (_Float16)a[0]; ha[1] = (_Float16)a[1];
        ha[2] = (_Float16)a[2]; ha[3] = (_Float16)a[3];
        hs[0] = (_Float16)s[0]; hs[1] = (_Float16)s[1];
        hs[2] = (_Float16)s[2]; hs[3] = (_Float16)s[3];
        wa[kt] = ha;  wsd[kt] = hs;
    }

    // B-fragments from z16[mrow-1]; rows with t==0 use z_prev = 0.
    const int mrow = m0 + col;
    const bool t0  = (mrow & (T_ - 1)) == 0;
    const int zrow = t0 ? mrow : (mrow - 1);
    h4_t zk[4];
    #pragma unroll
    for (int kt = 0; kt < 4; ++kt) {
        zk[kt] = *reinterpret_cast<const h4_t*>(&z16[zrow * 64 + kt * 16 + 4 * g]);
        if (t0)
            zk[kt] = (h4_t){(_Float16)0, (_Float16)0, (_Float16)0, (_Float16)0};
    }

    const int off = mrow * 64 + 16 * w + 4 * g;
    f4 am  = *reinterpret_cast<const f4*>(&pre_mu [off]);
    f4 as_ = *reinterpret_cast<const f4*>(&pre_std[off]);
    const f4 ev = *reinterpret_cast<const f4*>(&eps[off]);

    #pragma unroll
    for (int kt = 0; kt < 4; ++kt) {
        am  = __builtin_amdgcn_mfma_f32_16x16x16f16(wa[kt],  zk[kt], am,  0, 0, 0);
        as_ = __builtin_amdgcn_mfma_f32_16x16x16f16(wsd[kt], zk[kt], as_, 0, 0, 0);
    }

    f4 sd4, z4;
    #pragma unroll
    for (int i = 0; i < 4; ++i) {
        const float sx = as_[i];
        const float sp = (sx > 20.0f) ? sx : __logf(1.0f + __expf(sx));
        const float sd = sp + 1e-4f;
        sd4[i] = sd;
        z4[i]  = fmaf(ev[i], sd, am[i]);
    }

    float* __restrict__ zo  = out;
    float* __restrict__ muo = out + M_ * Z_;
    float* __restrict__ sdo = out + 2 * M_ * Z_;
    *reinterpret_cast<f4*>(&zo[off])  = z4;
    *reinterpret_cast<f4*>(&muo[off]) = am;
    *reinterpret_cast<f4*>(&sdo[off]) = sd4;
}

extern "C" void kernel_launch(void* const* d_in, const int* in_sizes, int n_in,
                              void* d_out, int out_size, void* d_ws, size_t ws_size,
                              hipStream_t stream) {
    const float* input_q = (const float*)d_in[0];  // [B, T, H]
    const float* eps     = (const float*)d_in[1];  // [B, T, Z]
    const float* W_mu    = (const float*)d_in[2];  // [Z, H+Z]
    const float* b_mu    = (const float*)d_in[3];  // [Z]
    const float* W_std   = (const float*)d_in[4];  // [Z, H+Z]
    const float* b_std   = (const float*)d_in[5];  // [Z]
    float* out = (float*)d_out;

    // workspace layout: pre_mu | pre_std (f32, 33.5 MB each) | z16 (f16, 16.7 MB)
    float*    pre_mu  = (float*)d_ws;
    float*    pre_std = pre_mu + (size_t)M_ * Z_;
    _Float16* z16     = (_Float16*)(pre_std + (size_t)M_ * Z_);

    precompute_kernel<<<M_ / 64, 256, 0, stream>>>(
        input_q, W_mu, W_std, b_mu, b_std, pre_mu, pre_std);

    recurrent_kernel<<<B_ / 16, 256, 0, stream>>>(
        pre_mu, pre_std, eps, W_mu, W_std, z16);

    finalize_kernel<<<M_ / 16, 256, 0, stream>>>(
        pre_mu, pre_std, eps, W_mu, W_std, z16, out);
}

// Round 14
// 642.972 us; speedup vs baseline: 2.2608x; 1.3278x over previous
//
#include <hip/hip_runtime.h>
#include <math.h>
#include <stdint.h>

#define B_ 128
#define T_ 1024
#define H_ 256
#define Z_ 64
#define M_ (B_ * T_)   // 131072 rows

typedef float     f4   __attribute__((ext_vector_type(4)));
typedef _Float16  h4_t __attribute__((ext_vector_type(4)));

// ---------------------------------------------------------------------------
// Kernel 1: precompute the non-recurrent part of both matmuls (unchanged).
// ---------------------------------------------------------------------------
__global__ __launch_bounds__(256) void precompute_kernel(
    const float* __restrict__ Hm,    // [M_, 256]
    const float* __restrict__ Wmu,   // [64, 320]
    const float* __restrict__ Wstd,  // [64, 320]
    const float* __restrict__ bmu,   // [64]
    const float* __restrict__ bstd,  // [64]
    float* __restrict__ pre_mu,      // [M_, 64]
    float* __restrict__ pre_std)     // [M_, 64]
{
    const int tid = threadIdx.x;
    const int ty = tid >> 4;
    const int tx = tid & 15;
    const int m0 = blockIdx.x * 64;

    __shared__ float Ash[64][17];
    __shared__ float Wm[64][17];
    __shared__ float Ws[64][17];

    float accm[4][4] = {};
    float accs[4][4] = {};

    const int lrow = tid >> 2;
    const int lk   = (tid & 3) * 4;

    for (int k0 = 0; k0 < 256; k0 += 16) {
        float4 av  = *reinterpret_cast<const float4*>(&Hm[(size_t)(m0 + lrow) * H_ + k0 + lk]);
        float4 wmv = *reinterpret_cast<const float4*>(&Wmu[(size_t)lrow * 320 + k0 + lk]);
        float4 wsv = *reinterpret_cast<const float4*>(&Wstd[(size_t)lrow * 320 + k0 + lk]);
        __syncthreads();
        Ash[lrow][lk + 0] = av.x;  Ash[lrow][lk + 1] = av.y;
        Ash[lrow][lk + 2] = av.z;  Ash[lrow][lk + 3] = av.w;
        Wm[lrow][lk + 0] = wmv.x;  Wm[lrow][lk + 1] = wmv.y;
        Wm[lrow][lk + 2] = wmv.z;  Wm[lrow][lk + 3] = wmv.w;
        Ws[lrow][lk + 0] = wsv.x;  Ws[lrow][lk + 1] = wsv.y;
        Ws[lrow][lk + 2] = wsv.z;  Ws[lrow][lk + 3] = wsv.w;
        __syncthreads();

        #pragma unroll
        for (int kk = 0; kk < 16; ++kk) {
            float a4[4], wm4[4], ws4[4];
            #pragma unroll
            for (int i = 0; i < 4; ++i) a4[i] = Ash[ty * 4 + i][kk];
            #pragma unroll
            for (int jj = 0; jj < 4; ++jj) wm4[jj] = Wm[tx * 4 + jj][kk];
            #pragma unroll
            for (int jj = 0; jj < 4; ++jj) ws4[jj] = Ws[tx * 4 + jj][kk];
            #pragma unroll
            for (int i = 0; i < 4; ++i)
                #pragma unroll
                for (int jj = 0; jj < 4; ++jj) {
                    accm[i][jj] += a4[i] * wm4[jj];
                    accs[i][jj] += a4[i] * ws4[jj];
                }
        }
    }

    float4 bm = *reinterpret_cast<const float4*>(&bmu[tx * 4]);
    float4 bs = *reinterpret_cast<const float4*>(&bstd[tx * 4]);
    #pragma unroll
    for (int i = 0; i < 4; ++i) {
        const size_t m = (size_t)(m0 + ty * 4 + i);
        float4 om, os;
        om.x = accm[i][0] + bm.x;  om.y = accm[i][1] + bm.y;
        om.z = accm[i][2] + bm.z;  om.w = accm[i][3] + bm.w;
        os.x = accs[i][0] + bs.x;  os.y = accs[i][1] + bs.y;
        os.z = accs[i][2] + bs.z;  os.w = accs[i][3] + bs.w;
        *reinterpret_cast<float4*>(&pre_mu[m * Z_ + tx * 4])  = om;
        *reinterpret_cast<float4*>(&pre_std[m * Z_ + tx * 4]) = os;
    }
}

// ---------------------------------------------------------------------------
// Kernel 2: MFMA recurrence, 4-wave rt-split, state-only output, UNROLL-4.
//
// R13 lesson: the depth-3 prefetch "rotation" (pmA=pmB;...;pmC=pmN register
// copies at loop bottom) forces a wait on the load issued THAT iteration ->
// effective prefetch depth 1 (~600 cy) < HBM latency (~900 cy): ~400 cy
// stall/step. Fix: unroll t-loop by 4 with bank u = t&3 statically indexed;
// the load for t+4 writes bank u AFTER its consumption at t, and is next
// read 4 iterations (~2400 cy) later. No copies. Same banking fixes the
// z16-store register reuse (R12's residual).
//
// Structure per R11-R13: 4 waves split the 64 z-rows (wave w = rows
// [16w,16w+16), 8 MFMAs each on separate SIMDs); z exchanged via padded
// LDS tile zbuf[2][16][72]; sync = raw "lgkmcnt(0); s_barrier" (NO
// __syncthreads -> no vmcnt drain, R1); 16x16x16 D->B fragment identity
// feeds z back with only f32->f16 converts (verified R9-R13 passing).
// ---------------------------------------------------------------------------
__global__ __launch_bounds__(256)
__attribute__((amdgpu_waves_per_eu(1, 1)))
void recurrent_kernel(
    const float* __restrict__ pre_mu,   // [M_, 64]
    const float* __restrict__ pre_std,  // [M_, 64]
    const float* __restrict__ eps,      // [B_, T_, 64]
    const float* __restrict__ Wmu,      // [64, 320]
    const float* __restrict__ Wstd,     // [64, 320]
    _Float16* __restrict__ z16)         // [B_, T_, 64] f16 state
{
    const int tid = threadIdx.x;
    const int w   = tid >> 6;          // wave = output row tile rt
    const int l   = tid & 63;
    const int col = l & 15;            // batch row within the 16-group
    const int g   = (l >> 4) & 3;      // 0..3
    const int b0  = blockIdx.x * 16;

    // A-fragments, rows [16w,16w+16): wa/wsd[kt], 8 x h4 = 16 VGPRs.
    h4_t wa[4], wsd[4];
    #pragma unroll
    for (int kt = 0; kt < 4; ++kt) {
        const int off = (w * 16 + col) * 320 + 256 + kt * 16 + 4 * g;
        const f4 a = *reinterpret_cast<const f4*>(&Wmu[off]);
        const f4 s = *reinterpret_cast<const f4*>(&Wstd[off]);
        h4_t ha, hs;
        ha[0] = (_Float16)a[0]; ha[1] = (_Float16)a[1];
        ha[2] = (_Float16)a[2]; ha[3] = (_Float16)a[3];
        hs[0] = (_Float16)s[0]; hs[1] = (_Float16)s[1];
        hs[2] = (_Float16)s[2]; hs[3] = (_Float16)s[3];
        wa[kt] = ha;  wsd[kt] = hs;
        asm volatile("" : "+v"(wa[kt]));
        asm volatile("" : "+v"(wsd[kt]));
    }

    // z exchange tile: [buf][col][row], row-pad 64->72 (144B col stride)
    __shared__ _Float16 zbuf[2][16][72];
    for (int i = tid; i < 2 * 16 * 72; i += 256)
        (&zbuf[0][0][0])[i] = (_Float16)0.0f;
    __syncthreads();   // one-time init barrier (outside loop: drain is fine)

    // this wave's global row slot: ((b0+col)*T + t)*64 + 16w + 4g
    const int rbase = ((b0 + col) * T_) * 64 + 16 * w + 4 * g;

    // prefetch banks: bank u serves steps t with t&3==u (depth 4, no copies)
    f4 pm[4], ps[4], ev[4];
    #pragma unroll
    for (int u = 0; u < 4; ++u) {
        pm[u] = *reinterpret_cast<const f4*>(&pre_mu [rbase + u * 64]);
        ps[u] = *reinterpret_cast<const f4*>(&pre_std[rbase + u * 64]);
        ev[u] = *reinterpret_cast<const f4*>(&eps    [rbase + u * 64]);
    }

    const int zrd = col * 144 + 8 * g;          // byte addr base for B-frags
    const int zwr = col * 144 + (16 * w + 4 * g) * 2;

    for (int tb = 0; tb < T_; tb += 4) {
        #pragma unroll
        for (int u = 0; u < 4; ++u) {
            const int t = tb + u;

            // B-fragments of z_{t-1}; (t&1)==(u&1) since tb is mult of 4.
            const _Float16* zc = &zbuf[u & 1][0][0];
            h4_t zk0 = *reinterpret_cast<const h4_t*>(
                reinterpret_cast<const char*>(zc) + zrd);
            h4_t zk1 = *reinterpret_cast<const h4_t*>(
                reinterpret_cast<const char*>(zc) + zrd + 32);
            h4_t zk2 = *reinterpret_cast<const h4_t*>(
                reinterpret_cast<const char*>(zc) + zrd + 64);
            h4_t zk3 = *reinterpret_cast<const h4_t*>(
                reinterpret_cast<const char*>(zc) + zrd + 96);

            // D = W * z + pre (two interleaved 4-deep chains)
            f4 am = pm[u], as_ = ps[u];
            am  = __builtin_amdgcn_mfma_f32_16x16x16f16(wa[0],  zk0, am,  0, 0, 0);
            as_ = __builtin_amdgcn_mfma_f32_16x16x16f16(wsd[0], zk0, as_, 0, 0, 0);
            am  = __builtin_amdgcn_mfma_f32_16x16x16f16(wa[1],  zk1, am,  0, 0, 0);
            as_ = __builtin_amdgcn_mfma_f32_16x16x16f16(wsd[1], zk1, as_, 0, 0, 0);
            am  = __builtin_amdgcn_mfma_f32_16x16x16f16(wa[2],  zk2, am,  0, 0, 0);
            as_ = __builtin_amdgcn_mfma_f32_16x16x16f16(wsd[2], zk2, as_, 0, 0, 0);
            am  = __builtin_amdgcn_mfma_f32_16x16x16f16(wa[3],  zk3, am,  0, 0, 0);
            as_ = __builtin_amdgcn_mfma_f32_16x16x16f16(wsd[3], zk3, as_, 0, 0, 0);

            // epilogue: softplus, z (state only)
            h4_t zz;
            #pragma unroll
            for (int i = 0; i < 4; ++i) {
                const float sx = as_[i];
                const float sp = (sx > 20.0f) ? sx : __logf(1.0f + __expf(sx));
                const float sd = sp + 1e-4f;
                zz[i] = (_Float16)fmaf(ev[u][i], sd, am[i]);
            }

            // publish z slice for t+1 (LDS) + persist state (8B store)
            *reinterpret_cast<h4_t*>(
                reinterpret_cast<char*>(&zbuf[(u + 1) & 1][0][0]) + zwr) = zz;
            *reinterpret_cast<h4_t*>(&z16[rbase + t * 64]) = zz;

            // refill bank u for t+4 (consumed 4 iterations = ~2400 cy later)
            {
                const int idx = rbase + ((t + 4 < T_) ? (t + 4) : t) * 64;
                pm[u] = *reinterpret_cast<const f4*>(&pre_mu [idx]);
                ps[u] = *reinterpret_cast<const f4*>(&pre_std[idx]);
                ev[u] = *reinterpret_cast<const f4*>(&eps    [idx]);
            }

            // sync WITHOUT draining vmcnt (raw barrier, not __syncthreads)
            asm volatile("s_waitcnt lgkmcnt(0)\n\ts_barrier" ::: "memory");
        }
    }
}

// ---------------------------------------------------------------------------
// Kernel 3: feed-forward finalize (unchanged). Recomputes mu/std/z for all
// (b,t) from z16[b,t-1] with identical f16 math -> identical outputs.
// ---------------------------------------------------------------------------
__global__ __launch_bounds__(256) void finalize_kernel(
    const float* __restrict__ pre_mu,   // [M_, 64]
    const float* __restrict__ pre_std,  // [M_, 64]
    const float* __restrict__ eps,      // [B_, T_, 64]
    const float* __restrict__ Wmu,      // [64, 320]
    const float* __restrict__ Wstd,     // [64, 320]
    const _Float16* __restrict__ z16,   // [B_, T_, 64]
    float* __restrict__ out)            // z | mu | std, each [B_, T_, 64]
{
    const int tid = threadIdx.x;
    const int w   = tid >> 6;
    const int l   = tid & 63;
    const int col = l & 15;
    const int g   = (l >> 4) & 3;
    const int m0  = blockIdx.x * 16;

    h4_t wa[4], wsd[4];
    #pragma unroll
    for (int kt = 0; kt < 4; ++kt) {
        const int off = (w * 16 + col) * 320 + 256 + kt * 16 + 4 * g;
        const f4 a = *reinterpret_cast<const f4*>(&Wmu[off]);
        const f4 s = *reinterpret_cast<const f4*>(&Wstd[off]);
        h4_t ha, hs;
        ha[0] = (_Float16)a[0]; ha[1] = (_Float16)a[1];
        ha[2] = (_Float16)a[2]; ha[3] = (_Float16)a[3];
        hs[0] = (_Float16)s[0]; hs[1] = (_Float16)s[1];
        hs[2] = (_Float16)s[2]; hs[3] = (_Float16)s[3];
        wa[kt] = ha;  wsd[kt] = hs;
    }

    const int mrow = m0 + col;
    const bool t0  = (mrow & (T_ - 1)) == 0;
    const int zrow = t0 ? mrow : (mrow - 1);
    h4_t zk[4];
    #pragma unroll
    for (int kt = 0; kt < 4; ++kt) {
        zk[kt] = *reinterpret_cast<const h4_t*>(&z16[zrow * 64 + kt * 16 + 4 * g]);
        if (t0)
            zk[kt] = (h4_t){(_Float16)0, (_Float16)0, (_Float16)0, (_Float16)0};
    }

    const int off = mrow * 64 + 16 * w + 4 * g;
    f4 am  = *reinterpret_cast<const f4*>(&pre_mu [off]);
    f4 as_ = *reinterpret_cast<const f4*>(&pre_std[off]);
    const f4 ev = *reinterpret_cast<const f4*>(&eps[off]);

    #pragma unroll
    for (int kt = 0; kt < 4; ++kt) {
        am  = __builtin_amdgcn_mfma_f32_16x16x16f16(wa[kt],  zk[kt], am,  0, 0, 0);
        as_ = __builtin_amdgcn_mfma_f32_16x16x16f16(wsd[kt], zk[kt], as_, 0, 0, 0);
    }

    f4 sd4, z4;
    #pragma unroll
    for (int i = 0; i < 4; ++i) {
        const float sx = as_[i];
        const float sp = (sx > 20.0f) ? sx : __logf(1.0f + __expf(sx));
        const float sd = sp + 1e-4f;
        sd4[i] = sd;
        z4[i]  = fmaf(ev[i], sd, am[i]);
    }

    float* __restrict__ zo  = out;
    float* __restrict__ muo = out + M_ * Z_;
    float* __restrict__ sdo = out + 2 * M_ * Z_;
    *reinterpret_cast<f4*>(&zo[off])  = z4;
    *reinterpret_cast<f4*>(&muo[off]) = am;
    *reinterpret_cast<f4*>(&sdo[off]) = sd4;
}

extern "C" void kernel_launch(void* const* d_in, const int* in_sizes, int n_in,
                              void* d_out, int out_size, void* d_ws, size_t ws_size,
                              hipStream_t stream) {
    const float* input_q = (const float*)d_in[0];  // [B, T, H]
    const float* eps     = (const float*)d_in[1];  // [B, T, Z]
    const float* W_mu    = (const float*)d_in[2];  // [Z, H+Z]
    const float* b_mu    = (const float*)d_in[3];  // [Z]
    const float* W_std   = (const float*)d_in[4];  // [Z, H+Z]
    const float* b_std   = (const float*)d_in[5];  // [Z]
    float* out = (float*)d_out;

    // workspace layout: pre_mu | pre_std (f32) | z16 (f16)
    float*    pre_mu  = (float*)d_ws;
    float*    pre_std = pre_mu + (size_t)M_ * Z_;
    _Float16* z16     = (_Float16*)(pre_std + (size_t)M_ * Z_);

    precompute_kernel<<<M_ / 64, 256, 0, stream>>>(
        input_q, W_mu, W_std, b_mu, b_std, pre_mu, pre_std);

    recurrent_kernel<<<B_ / 16, 256, 0, stream>>>(
        pre_mu, pre_std, eps, W_mu, W_std, z16);

    finalize_kernel<<<M_ / 16, 256, 0, stream>>>(
        pre_mu, pre_std, eps, W_mu, W_std, z16, out);
}